// Round 10
// baseline (267.906 us; speedup 1.0000x reference)
//
#include <hip/hip_runtime.h>

// Atom_Atom_embedding_MP: batched KNN (k=16, self-excluded) + 3 MP layers.
//
// R9: (a) layers REVERTED to v1 lane=(point,k) (measured 39us; R7's (point,c)
// split regressed to 56us: o=32 masked-lane tax + serial gather chain).
// (b) knn v3: 16 queries/block share candidates via LDS tile (4KB chunks);
// each wave owns 4 queries, one ds_read_b128 per 64-candidate chunk reused
// across its 4 queries -> 16x less L2 traffic, 32-bit addressing. Batch id
// rides in xyz4.w (sentinel -1 for OOB). Pool + radix-bisect selection (R7,
// measured good) unchanged, per-query pool slots. LDS 36KB -> 4 blocks/CU.

#define N_PTS 16384
#define D 16
#define DIN 33
#define NEG 0.2f
#define GEPS 1e-5f
#define INFF 3.0e38f
#define INFU 0x7f800000u
#define SHRINK_AT 192
#define QPB 16

__global__ __launch_bounds__(256) void prep_kernel(const float* __restrict__ x,
                                                   const int* __restrict__ batch,
                                                   float4* __restrict__ xyz4, int n) {
  int i = blockIdx.x * 256 + threadIdx.x;
  if (i < n) xyz4[i] = make_float4(x[3*i], x[3*i+1], x[3*i+2], __int_as_float(batch[i]));
}

// Exact 16th-smallest bit pattern of pool (u-rows) via 31-step radix bisection.
__device__ __forceinline__ unsigned bisect16(unsigned u0, unsigned u1,
                                             unsigned u2, unsigned u3) {
  unsigned lo = 0u, hi = 0x7f800001u;
  for (int it = 0; it < 31; ++it) {
    const unsigned mid = lo + ((hi - lo) >> 1);
    const int c = __popcll(__ballot(u0 < mid)) + __popcll(__ballot(u1 < mid))
                + __popcll(__ballot(u2 < mid)) + __popcll(__ballot(u3 < mid));
    if (c >= 16) hi = mid; else lo = mid;
  }
  return lo;
}

// Tighten tau to EXACT 16th-smallest-so-far; compact pool to entries <= tau.
__device__ __forceinline__ int pool_shrink(float* __restrict__ pd, int* __restrict__ pi,
                                           int pcount, float& tau, int l,
                                           unsigned long long lmask) {
  __asm__ volatile("s_waitcnt lgkmcnt(0)" ::: "memory");
  unsigned u0 = INFU, u1 = INFU, u2 = INFU, u3 = INFU;
  int j0 = 0, j1 = 0, j2 = 0, j3 = 0;
  if (l       < pcount) { u0 = __float_as_uint(pd[l]);       j0 = pi[l]; }
  if (l + 64  < pcount) { u1 = __float_as_uint(pd[l + 64]);  j1 = pi[l + 64]; }
  if (l + 128 < pcount) { u2 = __float_as_uint(pd[l + 128]); j2 = pi[l + 128]; }
  if (l + 192 < pcount) { u3 = __float_as_uint(pd[l + 192]); j3 = pi[l + 192]; }
  const unsigned t = bisect16(u0, u1, u2, u3);
  tau = __uint_as_float(t);              // scan keeps strict d2 < tau
  int base = 0;
  { const bool k = u0 <= t; const unsigned long long m = __ballot(k);
    if (k) { const int pos = base + __popcll(m & lmask);
             pd[pos] = __uint_as_float(u0); pi[pos] = j0; }
    base += __popcll(m); }
  { const bool k = u1 <= t; const unsigned long long m = __ballot(k);
    if (k) { const int pos = base + __popcll(m & lmask);
             pd[pos] = __uint_as_float(u1); pi[pos] = j1; }
    base += __popcll(m); }
  { const bool k = u2 <= t; const unsigned long long m = __ballot(k);
    if (k) { const int pos = base + __popcll(m & lmask);
             pd[pos] = __uint_as_float(u2); pi[pos] = j2; }
    base += __popcll(m); }
  { const bool k = u3 <= t; const unsigned long long m = __ballot(k);
    if (k) { const int pos = base + __popcll(m & lmask);
             pd[pos] = __uint_as_float(u3); pi[pos] = j3; }
    base += __popcll(m); }
  return base;
}

// Final: exact top-16 SET (unordered) written straight to output.
__device__ __forceinline__ void pool_final16(const float* __restrict__ pd,
                                             const int* __restrict__ pi,
                                             int pcount, int q, int l,
                                             int* __restrict__ knn_idx,
                                             float* __restrict__ knn_d2) {
  __asm__ volatile("s_waitcnt lgkmcnt(0)" ::: "memory");
  const unsigned long long lmask = (1ull << l) - 1ull;
  unsigned u0 = INFU, u1 = INFU, u2 = INFU, u3 = INFU;
  int j0 = 0, j1 = 0, j2 = 0, j3 = 0;
  if (l       < pcount) { u0 = __float_as_uint(pd[l]);       j0 = pi[l]; }
  if (l + 64  < pcount) { u1 = __float_as_uint(pd[l + 64]);  j1 = pi[l + 64]; }
  if (l + 128 < pcount) { u2 = __float_as_uint(pd[l + 128]); j2 = pi[l + 128]; }
  if (l + 192 < pcount) { u3 = __float_as_uint(pd[l + 192]); j3 = pi[l + 192]; }
  const unsigned t = bisect16(u0, u1, u2, u3);
  int base = 0;
  { const bool k = u0 < t; const unsigned long long m = __ballot(k);
    if (k) { const int pos = base + __popcll(m & lmask);
             knn_idx[q*16+pos] = j0; knn_d2[q*16+pos] = __uint_as_float(u0); }
    base += __popcll(m); }
  { const bool k = u1 < t; const unsigned long long m = __ballot(k);
    if (k) { const int pos = base + __popcll(m & lmask);
             knn_idx[q*16+pos] = j1; knn_d2[q*16+pos] = __uint_as_float(u1); }
    base += __popcll(m); }
  { const bool k = u2 < t; const unsigned long long m = __ballot(k);
    if (k) { const int pos = base + __popcll(m & lmask);
             knn_idx[q*16+pos] = j2; knn_d2[q*16+pos] = __uint_as_float(u2); }
    base += __popcll(m); }
  { const bool k = u3 < t; const unsigned long long m = __ballot(k);
    if (k) { const int pos = base + __popcll(m & lmask);
             knn_idx[q*16+pos] = j3; knn_d2[q*16+pos] = __uint_as_float(u3); }
    base += __popcll(m); }
  const float tf = __uint_as_float(t);
  { const bool k = u0 == t; const unsigned long long m = __ballot(k);
    if (k) { const int pos = base + __popcll(m & lmask);
             if (pos < 16) { knn_idx[q*16+pos] = j0; knn_d2[q*16+pos] = tf; } }
    base += __popcll(m); }
  { const bool k = u1 == t; const unsigned long long m = __ballot(k);
    if (k) { const int pos = base + __popcll(m & lmask);
             if (pos < 16) { knn_idx[q*16+pos] = j1; knn_d2[q*16+pos] = tf; } }
    base += __popcll(m); }
  { const bool k = u2 == t; const unsigned long long m = __ballot(k);
    if (k) { const int pos = base + __popcll(m & lmask);
             if (pos < 16) { knn_idx[q*16+pos] = j2; knn_d2[q*16+pos] = tf; } }
    base += __popcll(m); }
  { const bool k = u3 == t; const unsigned long long m = __ballot(k);
    if (k) { const int pos = base + __popcll(m & lmask);
             if (pos < 16) { knn_idx[q*16+pos] = j3; knn_d2[q*16+pos] = tf; } }
    base += __popcll(m); }
}

__global__ __launch_bounds__(256) void knn_kernel(const float4* __restrict__ xyz4,
                                                  const int* __restrict__ batch,
                                                  int* __restrict__ knn_idx,
                                                  float* __restrict__ knn_d2, int n) {
  __shared__ float4 tile[256];          // 4KB candidate tile (shared by block)
  __shared__ float  pdv[QPB][256];      // 16KB per-query pools
  __shared__ int    piv[QPB][256];      // 16KB
  const int tid = threadIdx.x;
  const int w = tid >> 6, l = tid & 63;
  const int q0 = blockIdx.x * QPB;

  // block-union scan range (batch sorted; queries q0..q0+15 contiguous)
  const int bfirst = batch[q0], blast = batch[q0 + QPB - 1];
  int blo, bhi;
  { int a = 0, c = n; while (a < c) { int m = (a + c) >> 1; if (batch[m] <  bfirst) a = m + 1; else c = m; } blo = a; }
  { int a = blo, c = n; while (a < c) { int m = (a + c) >> 1; if (batch[m] <= blast) a = m + 1; else c = m; } bhi = a; }

  const int qa = q0 + w * 4;            // this wave's 4 queries
  float4 Q[4]; int qb[4];
#pragma unroll
  for (int t = 0; t < 4; ++t) { Q[t] = xyz4[qa + t]; qb[t] = __float_as_int(Q[t].w); }
  float tau[4] = {INFF, INFF, INFF, INFF};
  int   pc[4]  = {0, 0, 0, 0};
  const unsigned long long lmask = (1ull << l) - 1ull;

  for (int base = blo; base < bhi; base += 256) {
    {
      const int idx = base + tid;
      tile[tid] = (idx < bhi) ? xyz4[idx]
                              : make_float4(1e30f, 1e30f, 1e30f, __int_as_float(-1));
    }
    __syncthreads();
#pragma unroll
    for (int s = 0; s < 4; ++s) {
      const float4 P = tile[s * 64 + l];          // one read serves 4 queries
      const int j = base + s * 64 + l;
      const int pb = __float_as_int(P.w);
#pragma unroll
      for (int t = 0; t < 4; ++t) {
        const float dx = Q[t].x - P.x, dy = Q[t].y - P.y, dz = Q[t].z - P.z;
        const float d2 = dx*dx + dy*dy + dz*dz;
        const bool pass = (d2 < tau[t]) && (pb == qb[t]) && (j != qa + t);
        const unsigned long long m = __ballot(pass);
        if (m) {
          if (pass) { const int pos = pc[t] + __popcll(m & lmask);
                      pdv[w*4+t][pos] = d2; piv[w*4+t][pos] = j; }
          pc[t] += __popcll(m);
          if (pc[t] >= SHRINK_AT)
            pc[t] = pool_shrink(&pdv[w*4+t][0], &piv[w*4+t][0], pc[t], tau[t], l, lmask);
        }
      }
    }
    __syncthreads();
  }
#pragma unroll
  for (int t = 0; t < 4; ++t)
    pool_final16(&pdv[w*4+t][0], &piv[w*4+t][0], pc[t], qa + t, l, knn_idx, knn_d2);
}

__device__ __forceinline__ void load16(const float4* __restrict__ base, int row, float* dst) {
  float4 a = base[row*4+0], b = base[row*4+1], c = base[row*4+2], d = base[row*4+3];
  dst[0]=a.x;  dst[1]=a.y;  dst[2]=a.z;  dst[3]=a.w;
  dst[4]=b.x;  dst[5]=b.y;  dst[6]=b.z;  dst[7]=b.w;
  dst[8]=c.x;  dst[9]=c.y;  dst[10]=c.z; dst[11]=c.w;
  dst[12]=d.x; dst[13]=d.y; dst[14]=d.z; dst[15]=d.w;
}

__device__ __forceinline__ float lrelu(float x) {
  return fmaxf(x, 0.f) + NEG * fminf(x, 0.f);
}

// Layer v1 (measured 39us/layer): lane = (point, k); W1 via wave-uniform
// s_loads; shfl-tree k-sum; W2 from LDS; shfl GroupNorm.
__global__ __launch_bounds__(256) void layer_kernel(
    const float* __restrict__ in, const int* __restrict__ knn_idx,
    const float* __restrict__ knn_d2,
    const float* __restrict__ W1, const float* __restrict__ b1,
    const float* __restrict__ W2, const float* __restrict__ b2,
    const float* __restrict__ gamma, const float* __restrict__ beta,
    float* __restrict__ outb) {
  __shared__ float sW2[DIN * D];
  __shared__ float sb2[D], sg[D], sbt[D];
  const int tid = threadIdx.x;
  for (int t = tid; t < DIN * D; t += 256) sW2[t] = W2[t];
  if (tid < D) { sb2[tid] = b2[tid]; sg[tid] = gamma[tid]; sbt[tid] = beta[tid]; }
  __syncthreads();

  const int p = blockIdx.x * 16 + (tid >> 4);  // point
  const int c = tid & 15;                       // lane-col == neighbor index k
  const float4* in4 = (const float4*)in;

  float s[16], nf[16];
  load16(in4, p, s);
  const int   nb = knn_idx[p * 16 + c];
  const float dk = knn_d2 [p * 16 + c];
  load16(in4, nb, nf);

  float h[DIN];
#pragma unroll
  for (int o = 0; o < DIN; ++o) h[o] = b1[o] + dk * W1[32 * DIN + o];
#pragma unroll
  for (int i = 0; i < 16; ++i) {
    const float si = s[i], ni = nf[i];
#pragma unroll
    for (int o = 0; o < DIN; ++o) {
      h[o] += si * W1[i * DIN + o];
      h[o] += ni * W1[(16 + i) * DIN + o];
    }
  }
#pragma unroll
  for (int o = 0; o < DIN; ++o) h[o] = lrelu(h[o]);

#pragma unroll
  for (int o = 0; o < DIN; ++o) {
    float x = h[o];
    x += __shfl_xor(x, 1);
    x += __shfl_xor(x, 2);
    x += __shfl_xor(x, 4);
    x += __shfl_xor(x, 8);
    h[o] = x;
  }

  float m = sb2[c];
#pragma unroll
  for (int i = 0; i < DIN; ++i) m += h[i] * sW2[i * D + c];

  float sum = m;
  sum += __shfl_xor(sum, 1); sum += __shfl_xor(sum, 2); sum += __shfl_xor(sum, 4);
  const float mu = sum * 0.125f;
  const float dd = m - mu;
  float sq = dd * dd;
  sq += __shfl_xor(sq, 1); sq += __shfl_xor(sq, 2); sq += __shfl_xor(sq, 4);
  const float var = sq * 0.125f;
  float yv = dd * (1.0f / sqrtf(var + GEPS));
  yv = yv * sg[c] + sbt[c];

  const float selfc = in[p * 16 + c];
  outb[p * 16 + c] = selfc + lrelu(yv);
}

extern "C" void kernel_launch(void* const* d_in, const int* in_sizes, int n_in,
                              void* d_out, int out_size, void* d_ws, size_t ws_size,
                              hipStream_t stream) {
  const float* x     = (const float*)d_in[0];
  const float* yat   = (const float*)d_in[2];
  const float* W1    = (const float*)d_in[3];
  const float* b1    = (const float*)d_in[4];
  const float* W2    = (const float*)d_in[5];
  const float* b2    = (const float*)d_in[6];
  const float* gamma = (const float*)d_in[7];
  const float* beta  = (const float*)d_in[8];
  const int*   xb    = (const int*)d_in[9];
  float* out = (float*)d_out;

  char* ws = (char*)d_ws;
  float4* xyz4 = (float4*)(ws);
  int*    kidx = (int*)  (ws + 262144);
  float*  kd2  = (float*)(ws + 262144 + 1048576);
  float*  bufA = (float*)(ws + 262144 + 2*1048576);
  float*  bufB = (float*)(ws + 262144 + 3*1048576);

  prep_kernel<<<N_PTS / 256, 256, 0, stream>>>(x, xb, xyz4, N_PTS);
  knn_kernel<<<N_PTS / QPB, 256, 0, stream>>>(xyz4, xb, kidx, kd2, N_PTS);
  layer_kernel<<<N_PTS / 16, 256, 0, stream>>>(yat,  kidx, kd2,
      W1 + 0*DIN*DIN, b1 + 0*DIN, W2 + 0*DIN*D, b2 + 0*D, gamma + 0*D, beta + 0*D, bufA);
  layer_kernel<<<N_PTS / 16, 256, 0, stream>>>(bufA, kidx, kd2,
      W1 + 1*DIN*DIN, b1 + 1*DIN, W2 + 1*DIN*D, b2 + 1*D, gamma + 1*D, beta + 1*D, bufB);
  layer_kernel<<<N_PTS / 16, 256, 0, stream>>>(bufB, kidx, kd2,
      W1 + 2*DIN*DIN, b1 + 2*DIN, W2 + 2*DIN*D, b2 + 2*D, gamma + 2*D, beta + 2*D, out);
}

// Round 11
// 223.351 us; speedup vs baseline: 1.1995x; 1.1995x over previous
//
#include <hip/hip_runtime.h>

// Atom_Atom_embedding_MP: batched KNN (k=16, self-excluded) + 3 MP layers.
//
// R10: knn = R7 structure (wave-per-query, measured 95.5us, occupancy 72%) +
// 4x-unrolled fast path: full 256-cand tiles do 4 indep loads (const-offset),
// 4 d2, 4 cmp, ONE or-combined ballot; append machinery only on the rare
// taken path. Tail = proven 64-stride loop. [R9's LDS-tile variant REVERTED:
// 36KB LDS + 1024-block grid collapsed occupancy 72->30, 95->141us.]
// Layers: v1 (measured 39us) + W1/b1 staged in LDS (broadcast ds_reads
// replace the per-wave 4.4KB SGPR stream -> tests the s_load-stall theory).

#define N_PTS 16384
#define D 16
#define DIN 33
#define NEG 0.2f
#define GEPS 1e-5f
#define INFF 3.0e38f
#define INFU 0x7f800000u
#define SHRINK_AT 192

__global__ __launch_bounds__(256) void prep_kernel(const float* __restrict__ x,
                                                   float4* __restrict__ xyz4, int n) {
  int i = blockIdx.x * 256 + threadIdx.x;
  if (i < n) xyz4[i] = make_float4(x[3*i], x[3*i+1], x[3*i+2], 0.f);
}

// Exact 16th-smallest bit pattern of pool (u-rows) via 31-step radix bisection.
__device__ __forceinline__ unsigned bisect16(unsigned u0, unsigned u1,
                                             unsigned u2, unsigned u3) {
  unsigned lo = 0u, hi = 0x7f800001u;
  for (int it = 0; it < 31; ++it) {
    const unsigned mid = lo + ((hi - lo) >> 1);
    const int c = __popcll(__ballot(u0 < mid)) + __popcll(__ballot(u1 < mid))
                + __popcll(__ballot(u2 < mid)) + __popcll(__ballot(u3 < mid));
    if (c >= 16) hi = mid; else lo = mid;
  }
  return lo;
}

// Tighten tau to EXACT 16th-smallest-so-far; compact pool to entries <= tau.
__device__ __forceinline__ int pool_shrink(float* __restrict__ pd, int* __restrict__ pi,
                                           int pcount, float& tau, int l,
                                           unsigned long long lmask) {
  __asm__ volatile("s_waitcnt lgkmcnt(0)" ::: "memory");
  unsigned u0 = INFU, u1 = INFU, u2 = INFU, u3 = INFU;
  int j0 = 0, j1 = 0, j2 = 0, j3 = 0;
  if (l       < pcount) { u0 = __float_as_uint(pd[l]);       j0 = pi[l]; }
  if (l + 64  < pcount) { u1 = __float_as_uint(pd[l + 64]);  j1 = pi[l + 64]; }
  if (l + 128 < pcount) { u2 = __float_as_uint(pd[l + 128]); j2 = pi[l + 128]; }
  if (l + 192 < pcount) { u3 = __float_as_uint(pd[l + 192]); j3 = pi[l + 192]; }
  const unsigned t = bisect16(u0, u1, u2, u3);
  tau = __uint_as_float(t);              // scan keeps strict d2 < tau
  int base = 0;
  { const bool k = u0 <= t; const unsigned long long m = __ballot(k);
    if (k) { const int pos = base + __popcll(m & lmask);
             pd[pos] = __uint_as_float(u0); pi[pos] = j0; }
    base += __popcll(m); }
  { const bool k = u1 <= t; const unsigned long long m = __ballot(k);
    if (k) { const int pos = base + __popcll(m & lmask);
             pd[pos] = __uint_as_float(u1); pi[pos] = j1; }
    base += __popcll(m); }
  { const bool k = u2 <= t; const unsigned long long m = __ballot(k);
    if (k) { const int pos = base + __popcll(m & lmask);
             pd[pos] = __uint_as_float(u2); pi[pos] = j2; }
    base += __popcll(m); }
  { const bool k = u3 <= t; const unsigned long long m = __ballot(k);
    if (k) { const int pos = base + __popcll(m & lmask);
             pd[pos] = __uint_as_float(u3); pi[pos] = j3; }
    base += __popcll(m); }
  return base;
}

// Final: exact top-16 SET (unordered) written straight to output.
__device__ __forceinline__ void pool_final16(const float* __restrict__ pd,
                                             const int* __restrict__ pi,
                                             int pcount, int q, int l,
                                             int* __restrict__ knn_idx,
                                             float* __restrict__ knn_d2) {
  __asm__ volatile("s_waitcnt lgkmcnt(0)" ::: "memory");
  const unsigned long long lmask = (1ull << l) - 1ull;
  unsigned u0 = INFU, u1 = INFU, u2 = INFU, u3 = INFU;
  int j0 = 0, j1 = 0, j2 = 0, j3 = 0;
  if (l       < pcount) { u0 = __float_as_uint(pd[l]);       j0 = pi[l]; }
  if (l + 64  < pcount) { u1 = __float_as_uint(pd[l + 64]);  j1 = pi[l + 64]; }
  if (l + 128 < pcount) { u2 = __float_as_uint(pd[l + 128]); j2 = pi[l + 128]; }
  if (l + 192 < pcount) { u3 = __float_as_uint(pd[l + 192]); j3 = pi[l + 192]; }
  const unsigned t = bisect16(u0, u1, u2, u3);
  int base = 0;
  { const bool k = u0 < t; const unsigned long long m = __ballot(k);
    if (k) { const int pos = base + __popcll(m & lmask);
             knn_idx[q*16+pos] = j0; knn_d2[q*16+pos] = __uint_as_float(u0); }
    base += __popcll(m); }
  { const bool k = u1 < t; const unsigned long long m = __ballot(k);
    if (k) { const int pos = base + __popcll(m & lmask);
             knn_idx[q*16+pos] = j1; knn_d2[q*16+pos] = __uint_as_float(u1); }
    base += __popcll(m); }
  { const bool k = u2 < t; const unsigned long long m = __ballot(k);
    if (k) { const int pos = base + __popcll(m & lmask);
             knn_idx[q*16+pos] = j2; knn_d2[q*16+pos] = __uint_as_float(u2); }
    base += __popcll(m); }
  { const bool k = u3 < t; const unsigned long long m = __ballot(k);
    if (k) { const int pos = base + __popcll(m & lmask);
             knn_idx[q*16+pos] = j3; knn_d2[q*16+pos] = __uint_as_float(u3); }
    base += __popcll(m); }
  const float tf = __uint_as_float(t);
  { const bool k = u0 == t; const unsigned long long m = __ballot(k);
    if (k) { const int pos = base + __popcll(m & lmask);
             if (pos < 16) { knn_idx[q*16+pos] = j0; knn_d2[q*16+pos] = tf; } }
    base += __popcll(m); }
  { const bool k = u1 == t; const unsigned long long m = __ballot(k);
    if (k) { const int pos = base + __popcll(m & lmask);
             if (pos < 16) { knn_idx[q*16+pos] = j1; knn_d2[q*16+pos] = tf; } }
    base += __popcll(m); }
  { const bool k = u2 == t; const unsigned long long m = __ballot(k);
    if (k) { const int pos = base + __popcll(m & lmask);
             if (pos < 16) { knn_idx[q*16+pos] = j2; knn_d2[q*16+pos] = tf; } }
    base += __popcll(m); }
  { const bool k = u3 == t; const unsigned long long m = __ballot(k);
    if (k) { const int pos = base + __popcll(m & lmask);
             if (pos < 16) { knn_idx[q*16+pos] = j3; knn_d2[q*16+pos] = tf; } }
    base += __popcll(m); }
}

__global__ __launch_bounds__(256) void knn_kernel(const float4* __restrict__ xyz4,
                                                  const int* __restrict__ batch,
                                                  int* __restrict__ knn_idx,
                                                  float* __restrict__ knn_d2, int n) {
  __shared__ float pd[4][256];
  __shared__ int   pi[4][256];
  const int tid = threadIdx.x;
  const int w = tid >> 6;
  const int l = tid & 63;
  const int q = blockIdx.x * 4 + w;

  const float4 Q = xyz4[q];
  const int b = batch[q];
  int lo, hi;
  { int a = 0, c = n; while (a < c) { int m = (a + c) >> 1; if (batch[m] <  b) a = m + 1; else c = m; } lo = a; }
  { int a = lo, c = n; while (a < c) { int m = (a + c) >> 1; if (batch[m] <= b) a = m + 1; else c = m; } hi = a; }

  const unsigned long long lmask = (1ull << l) - 1ull;
  float tau = INFF;
  int pcount = 0;                       // wave-uniform (ballot-derived)

  // ---- fast path: full 256-candidate tiles, append machinery branch-skipped
  int j0 = lo;
  for (; j0 + 256 <= hi; j0 += 256) {
    const int ja = j0 + l;
    const float4 P0 = xyz4[ja];
    const float4 P1 = xyz4[ja + 64];    // const offsets fold into the load
    const float4 P2 = xyz4[ja + 128];
    const float4 P3 = xyz4[ja + 192];
    const float dx0 = Q.x-P0.x, dy0 = Q.y-P0.y, dz0 = Q.z-P0.z;
    const float dx1 = Q.x-P1.x, dy1 = Q.y-P1.y, dz1 = Q.z-P1.z;
    const float dx2 = Q.x-P2.x, dy2 = Q.y-P2.y, dz2 = Q.z-P2.z;
    const float dx3 = Q.x-P3.x, dy3 = Q.y-P3.y, dz3 = Q.z-P3.z;
    const float d20 = dx0*dx0 + dy0*dy0 + dz0*dz0;
    const float d21 = dx1*dx1 + dy1*dy1 + dz1*dz1;
    const float d22 = dx2*dx2 + dy2*dy2 + dz2*dz2;
    const float d23 = dx3*dx3 + dy3*dy3 + dz3*dz3;
    const bool p0 = (d20 < tau) && (ja        != q);
    const bool p1 = (d21 < tau) && (ja + 64   != q);
    const bool p2 = (d22 < tau) && (ja + 128  != q);
    const bool p3 = (d23 < tau) && (ja + 192  != q);
    if (__ballot(p0 | p1 | p2 | p3)) {  // rare after tau tightens
      { const unsigned long long m = __ballot(p0);
        if (m) { if (p0) { const int pos = pcount + __popcll(m & lmask);
                           pd[w][pos] = d20; pi[w][pos] = ja; }
                 pcount += __popcll(m);
                 if (pcount >= SHRINK_AT)
                   pcount = pool_shrink(&pd[w][0], &pi[w][0], pcount, tau, l, lmask); } }
      { const unsigned long long m = __ballot(p1);
        if (m) { if (p1) { const int pos = pcount + __popcll(m & lmask);
                           pd[w][pos] = d21; pi[w][pos] = ja + 64; }
                 pcount += __popcll(m);
                 if (pcount >= SHRINK_AT)
                   pcount = pool_shrink(&pd[w][0], &pi[w][0], pcount, tau, l, lmask); } }
      { const unsigned long long m = __ballot(p2);
        if (m) { if (p2) { const int pos = pcount + __popcll(m & lmask);
                           pd[w][pos] = d22; pi[w][pos] = ja + 128; }
                 pcount += __popcll(m);
                 if (pcount >= SHRINK_AT)
                   pcount = pool_shrink(&pd[w][0], &pi[w][0], pcount, tau, l, lmask); } }
      { const unsigned long long m = __ballot(p3);
        if (m) { if (p3) { const int pos = pcount + __popcll(m & lmask);
                           pd[w][pos] = d23; pi[w][pos] = ja + 192; }
                 pcount += __popcll(m);
                 if (pcount >= SHRINK_AT)
                   pcount = pool_shrink(&pd[w][0], &pi[w][0], pcount, tau, l, lmask); } }
    }
  }
  // ---- tail: proven 64-stride loop
  for (; j0 < hi; j0 += 64) {
    const int j = j0 + l;
    bool pass = false; float d2 = 0.f;
    if (j < hi) {
      const float4 P = xyz4[j];
      const float dx = Q.x - P.x, dy = Q.y - P.y, dz = Q.z - P.z;
      d2 = dx*dx + dy*dy + dz*dz;
      pass = (d2 < tau) && (j != q);
    }
    const unsigned long long m = __ballot(pass);
    if (m) {
      if (pass) {
        const int pos = pcount + __popcll(m & lmask);
        pd[w][pos] = d2; pi[w][pos] = j;
      }
      pcount += __popcll(m);
      if (pcount >= SHRINK_AT)
        pcount = pool_shrink(&pd[w][0], &pi[w][0], pcount, tau, l, lmask);
    }
  }
  pool_final16(&pd[w][0], &pi[w][0], pcount, q, l, knn_idx, knn_d2);
}

__device__ __forceinline__ void load16(const float4* __restrict__ base, int row, float* dst) {
  float4 a = base[row*4+0], b = base[row*4+1], c = base[row*4+2], d = base[row*4+3];
  dst[0]=a.x;  dst[1]=a.y;  dst[2]=a.z;  dst[3]=a.w;
  dst[4]=b.x;  dst[5]=b.y;  dst[6]=b.z;  dst[7]=b.w;
  dst[8]=c.x;  dst[9]=c.y;  dst[10]=c.z; dst[11]=c.w;
  dst[12]=d.x; dst[13]=d.y; dst[14]=d.z; dst[15]=d.w;
}

__device__ __forceinline__ float lrelu(float x) {
  return fmaxf(x, 0.f) + NEG * fminf(x, 0.f);
}

// Layer v1 + LDS-staged W1/b1: lane = (point, k); W1 matvec reads broadcast
// ds_reads (vector pipe, pipelined) instead of a 4.4KB/wave SGPR stream.
__global__ __launch_bounds__(256) void layer_kernel(
    const float* __restrict__ in, const int* __restrict__ knn_idx,
    const float* __restrict__ knn_d2,
    const float* __restrict__ W1, const float* __restrict__ b1,
    const float* __restrict__ W2, const float* __restrict__ b2,
    const float* __restrict__ gamma, const float* __restrict__ beta,
    float* __restrict__ outb) {
  __shared__ float sW1[DIN * DIN];
  __shared__ float sb1[DIN];
  __shared__ float sW2[DIN * D];
  __shared__ float sb2[D], sg[D], sbt[D];
  const int tid = threadIdx.x;
  for (int t = tid; t < DIN * DIN; t += 256) sW1[t] = W1[t];
  for (int t = tid; t < DIN * D;   t += 256) sW2[t] = W2[t];
  if (tid < DIN) sb1[tid] = b1[tid];
  if (tid < D) { sb2[tid] = b2[tid]; sg[tid] = gamma[tid]; sbt[tid] = beta[tid]; }
  __syncthreads();

  const int p = blockIdx.x * 16 + (tid >> 4);  // point
  const int c = tid & 15;                       // lane-col == neighbor index k
  const float4* in4 = (const float4*)in;

  float s[16], nf[16];
  load16(in4, p, s);
  const int   nb = knn_idx[p * 16 + c];
  const float dk = knn_d2 [p * 16 + c];
  load16(in4, nb, nf);

  float h[DIN];
#pragma unroll
  for (int o = 0; o < DIN; ++o) h[o] = sb1[o] + dk * sW1[32 * DIN + o];
#pragma unroll
  for (int i = 0; i < 16; ++i) {
    const float si = s[i], ni = nf[i];
#pragma unroll
    for (int o = 0; o < DIN; ++o) {
      h[o] += si * sW1[i * DIN + o];
      h[o] += ni * sW1[(16 + i) * DIN + o];
    }
  }
#pragma unroll
  for (int o = 0; o < DIN; ++o) h[o] = lrelu(h[o]);

#pragma unroll
  for (int o = 0; o < DIN; ++o) {
    float x = h[o];
    x += __shfl_xor(x, 1);
    x += __shfl_xor(x, 2);
    x += __shfl_xor(x, 4);
    x += __shfl_xor(x, 8);
    h[o] = x;
  }

  float m = sb2[c];
#pragma unroll
  for (int i = 0; i < DIN; ++i) m += h[i] * sW2[i * D + c];

  float sum = m;
  sum += __shfl_xor(sum, 1); sum += __shfl_xor(sum, 2); sum += __shfl_xor(sum, 4);
  const float mu = sum * 0.125f;
  const float dd = m - mu;
  float sq = dd * dd;
  sq += __shfl_xor(sq, 1); sq += __shfl_xor(sq, 2); sq += __shfl_xor(sq, 4);
  const float var = sq * 0.125f;
  float yv = dd * (1.0f / sqrtf(var + GEPS));
  yv = yv * sg[c] + sbt[c];

  const float selfc = in[p * 16 + c];
  outb[p * 16 + c] = selfc + lrelu(yv);
}

extern "C" void kernel_launch(void* const* d_in, const int* in_sizes, int n_in,
                              void* d_out, int out_size, void* d_ws, size_t ws_size,
                              hipStream_t stream) {
  const float* x     = (const float*)d_in[0];
  const float* yat   = (const float*)d_in[2];
  const float* W1    = (const float*)d_in[3];
  const float* b1    = (const float*)d_in[4];
  const float* W2    = (const float*)d_in[5];
  const float* b2    = (const float*)d_in[6];
  const float* gamma = (const float*)d_in[7];
  const float* beta  = (const float*)d_in[8];
  const int*   xb    = (const int*)d_in[9];
  float* out = (float*)d_out;

  char* ws = (char*)d_ws;
  float4* xyz4 = (float4*)(ws);
  int*    kidx = (int*)  (ws + 262144);
  float*  kd2  = (float*)(ws + 262144 + 1048576);
  float*  bufA = (float*)(ws + 262144 + 2*1048576);
  float*  bufB = (float*)(ws + 262144 + 3*1048576);

  prep_kernel<<<N_PTS / 256, 256, 0, stream>>>(x, xyz4, N_PTS);
  knn_kernel<<<N_PTS / 4, 256, 0, stream>>>(xyz4, xb, kidx, kd2, N_PTS);
  layer_kernel<<<N_PTS / 16, 256, 0, stream>>>(yat,  kidx, kd2,
      W1 + 0*DIN*DIN, b1 + 0*DIN, W2 + 0*DIN*D, b2 + 0*D, gamma + 0*D, beta + 0*D, bufA);
  layer_kernel<<<N_PTS / 16, 256, 0, stream>>>(bufA, kidx, kd2,
      W1 + 1*DIN*DIN, b1 + 1*DIN, W2 + 1*DIN*D, b2 + 1*D, gamma + 1*D, beta + 1*D, bufB);
  layer_kernel<<<N_PTS / 16, 256, 0, stream>>>(bufB, kidx, kd2,
      W1 + 2*DIN*DIN, b1 + 2*DIN, W2 + 2*DIN*D, b2 + 2*D, gamma + 2*D, beta + 2*D, out);
}

// Round 13
// 205.692 us; speedup vs baseline: 1.3025x; 1.0859x over previous
//
#include <hip/hip_runtime.h>

// Atom_Atom_embedding_MP: batched KNN (k=16, self-excluded) + 3 MP layers.
//
// R11 (resubmitted R12 after infra failure): layers restructured via
// u-decomposition: feat@W1 = self@W1_top + nbr@W1_mid + d2*W1row32, and
// self@W1_top is shared by all 16 neighbors -> compute u = b1 + self@W1_top
// once per point (cooperative, 32 FMA/lane, same-wave LDS exchange w/
// lgkmcnt(0) - the knn-pool-proven pattern), then lane=(point,k) does only
// nbr@W1_mid (528 FMA, 2.2KB s_load stream - half of v1). W1 kept as DIRECT
// GLOBAL reads (R10's LDS-W1 staging measured +5.4us/layer). knn unchanged
// (R10-measured 86.6us).

#define N_PTS 16384
#define D 16
#define DIN 33
#define NEG 0.2f
#define GEPS 1e-5f
#define INFF 3.0e38f
#define INFU 0x7f800000u
#define SHRINK_AT 192

__global__ __launch_bounds__(256) void prep_kernel(const float* __restrict__ x,
                                                   float4* __restrict__ xyz4, int n) {
  int i = blockIdx.x * 256 + threadIdx.x;
  if (i < n) xyz4[i] = make_float4(x[3*i], x[3*i+1], x[3*i+2], 0.f);
}

// Exact 16th-smallest bit pattern of pool (u-rows) via 31-step radix bisection.
__device__ __forceinline__ unsigned bisect16(unsigned u0, unsigned u1,
                                             unsigned u2, unsigned u3) {
  unsigned lo = 0u, hi = 0x7f800001u;
  for (int it = 0; it < 31; ++it) {
    const unsigned mid = lo + ((hi - lo) >> 1);
    const int c = __popcll(__ballot(u0 < mid)) + __popcll(__ballot(u1 < mid))
                + __popcll(__ballot(u2 < mid)) + __popcll(__ballot(u3 < mid));
    if (c >= 16) hi = mid; else lo = mid;
  }
  return lo;
}

// Tighten tau to EXACT 16th-smallest-so-far; compact pool to entries <= tau.
__device__ __forceinline__ int pool_shrink(float* __restrict__ pd, int* __restrict__ pi,
                                           int pcount, float& tau, int l,
                                           unsigned long long lmask) {
  __asm__ volatile("s_waitcnt lgkmcnt(0)" ::: "memory");
  unsigned u0 = INFU, u1 = INFU, u2 = INFU, u3 = INFU;
  int j0 = 0, j1 = 0, j2 = 0, j3 = 0;
  if (l       < pcount) { u0 = __float_as_uint(pd[l]);       j0 = pi[l]; }
  if (l + 64  < pcount) { u1 = __float_as_uint(pd[l + 64]);  j1 = pi[l + 64]; }
  if (l + 128 < pcount) { u2 = __float_as_uint(pd[l + 128]); j2 = pi[l + 128]; }
  if (l + 192 < pcount) { u3 = __float_as_uint(pd[l + 192]); j3 = pi[l + 192]; }
  const unsigned t = bisect16(u0, u1, u2, u3);
  tau = __uint_as_float(t);              // scan keeps strict d2 < tau
  int base = 0;
  { const bool k = u0 <= t; const unsigned long long m = __ballot(k);
    if (k) { const int pos = base + __popcll(m & lmask);
             pd[pos] = __uint_as_float(u0); pi[pos] = j0; }
    base += __popcll(m); }
  { const bool k = u1 <= t; const unsigned long long m = __ballot(k);
    if (k) { const int pos = base + __popcll(m & lmask);
             pd[pos] = __uint_as_float(u1); pi[pos] = j1; }
    base += __popcll(m); }
  { const bool k = u2 <= t; const unsigned long long m = __ballot(k);
    if (k) { const int pos = base + __popcll(m & lmask);
             pd[pos] = __uint_as_float(u2); pi[pos] = j2; }
    base += __popcll(m); }
  { const bool k = u3 <= t; const unsigned long long m = __ballot(k);
    if (k) { const int pos = base + __popcll(m & lmask);
             pd[pos] = __uint_as_float(u3); pi[pos] = j3; }
    base += __popcll(m); }
  return base;
}

// Final: exact top-16 SET (unordered) written straight to output.
__device__ __forceinline__ void pool_final16(const float* __restrict__ pd,
                                             const int* __restrict__ pi,
                                             int pcount, int q, int l,
                                             int* __restrict__ knn_idx,
                                             float* __restrict__ knn_d2) {
  __asm__ volatile("s_waitcnt lgkmcnt(0)" ::: "memory");
  const unsigned long long lmask = (1ull << l) - 1ull;
  unsigned u0 = INFU, u1 = INFU, u2 = INFU, u3 = INFU;
  int j0 = 0, j1 = 0, j2 = 0, j3 = 0;
  if (l       < pcount) { u0 = __float_as_uint(pd[l]);       j0 = pi[l]; }
  if (l + 64  < pcount) { u1 = __float_as_uint(pd[l + 64]);  j1 = pi[l + 64]; }
  if (l + 128 < pcount) { u2 = __float_as_uint(pd[l + 128]); j2 = pi[l + 128]; }
  if (l + 192 < pcount) { u3 = __float_as_uint(pd[l + 192]); j3 = pi[l + 192]; }
  const unsigned t = bisect16(u0, u1, u2, u3);
  int base = 0;
  { const bool k = u0 < t; const unsigned long long m = __ballot(k);
    if (k) { const int pos = base + __popcll(m & lmask);
             knn_idx[q*16+pos] = j0; knn_d2[q*16+pos] = __uint_as_float(u0); }
    base += __popcll(m); }
  { const bool k = u1 < t; const unsigned long long m = __ballot(k);
    if (k) { const int pos = base + __popcll(m & lmask);
             knn_idx[q*16+pos] = j1; knn_d2[q*16+pos] = __uint_as_float(u1); }
    base += __popcll(m); }
  { const bool k = u2 < t; const unsigned long long m = __ballot(k);
    if (k) { const int pos = base + __popcll(m & lmask);
             knn_idx[q*16+pos] = j2; knn_d2[q*16+pos] = __uint_as_float(u2); }
    base += __popcll(m); }
  { const bool k = u3 < t; const unsigned long long m = __ballot(k);
    if (k) { const int pos = base + __popcll(m & lmask);
             knn_idx[q*16+pos] = j3; knn_d2[q*16+pos] = __uint_as_float(u3); }
    base += __popcll(m); }
  const float tf = __uint_as_float(t);
  { const bool k = u0 == t; const unsigned long long m = __ballot(k);
    if (k) { const int pos = base + __popcll(m & lmask);
             if (pos < 16) { knn_idx[q*16+pos] = j0; knn_d2[q*16+pos] = tf; } }
    base += __popcll(m); }
  { const bool k = u1 == t; const unsigned long long m = __ballot(k);
    if (k) { const int pos = base + __popcll(m & lmask);
             if (pos < 16) { knn_idx[q*16+pos] = j1; knn_d2[q*16+pos] = tf; } }
    base += __popcll(m); }
  { const bool k = u2 == t; const unsigned long long m = __ballot(k);
    if (k) { const int pos = base + __popcll(m & lmask);
             if (pos < 16) { knn_idx[q*16+pos] = j2; knn_d2[q*16+pos] = tf; } }
    base += __popcll(m); }
  { const bool k = u3 == t; const unsigned long long m = __ballot(k);
    if (k) { const int pos = base + __popcll(m & lmask);
             if (pos < 16) { knn_idx[q*16+pos] = j3; knn_d2[q*16+pos] = tf; } }
    base += __popcll(m); }
}

__global__ __launch_bounds__(256) void knn_kernel(const float4* __restrict__ xyz4,
                                                  const int* __restrict__ batch,
                                                  int* __restrict__ knn_idx,
                                                  float* __restrict__ knn_d2, int n) {
  __shared__ float pd[4][256];
  __shared__ int   pi[4][256];
  const int tid = threadIdx.x;
  const int w = tid >> 6;
  const int l = tid & 63;
  const int q = blockIdx.x * 4 + w;

  const float4 Q = xyz4[q];
  const int b = batch[q];
  int lo, hi;
  { int a = 0, c = n; while (a < c) { int m = (a + c) >> 1; if (batch[m] <  b) a = m + 1; else c = m; } lo = a; }
  { int a = lo, c = n; while (a < c) { int m = (a + c) >> 1; if (batch[m] <= b) a = m + 1; else c = m; } hi = a; }

  const unsigned long long lmask = (1ull << l) - 1ull;
  float tau = INFF;
  int pcount = 0;                       // wave-uniform (ballot-derived)

  // ---- fast path: full 256-candidate tiles, append machinery branch-skipped
  int j0 = lo;
  for (; j0 + 256 <= hi; j0 += 256) {
    const int ja = j0 + l;
    const float4 P0 = xyz4[ja];
    const float4 P1 = xyz4[ja + 64];    // const offsets fold into the load
    const float4 P2 = xyz4[ja + 128];
    const float4 P3 = xyz4[ja + 192];
    const float dx0 = Q.x-P0.x, dy0 = Q.y-P0.y, dz0 = Q.z-P0.z;
    const float dx1 = Q.x-P1.x, dy1 = Q.y-P1.y, dz1 = Q.z-P1.z;
    const float dx2 = Q.x-P2.x, dy2 = Q.y-P2.y, dz2 = Q.z-P2.z;
    const float dx3 = Q.x-P3.x, dy3 = Q.y-P3.y, dz3 = Q.z-P3.z;
    const float d20 = dx0*dx0 + dy0*dy0 + dz0*dz0;
    const float d21 = dx1*dx1 + dy1*dy1 + dz1*dz1;
    const float d22 = dx2*dx2 + dy2*dy2 + dz2*dz2;
    const float d23 = dx3*dx3 + dy3*dy3 + dz3*dz3;
    const bool p0 = (d20 < tau) && (ja        != q);
    const bool p1 = (d21 < tau) && (ja + 64   != q);
    const bool p2 = (d22 < tau) && (ja + 128  != q);
    const bool p3 = (d23 < tau) && (ja + 192  != q);
    if (__ballot(p0 | p1 | p2 | p3)) {  // rare after tau tightens
      { const unsigned long long m = __ballot(p0);
        if (m) { if (p0) { const int pos = pcount + __popcll(m & lmask);
                           pd[w][pos] = d20; pi[w][pos] = ja; }
                 pcount += __popcll(m);
                 if (pcount >= SHRINK_AT)
                   pcount = pool_shrink(&pd[w][0], &pi[w][0], pcount, tau, l, lmask); } }
      { const unsigned long long m = __ballot(p1);
        if (m) { if (p1) { const int pos = pcount + __popcll(m & lmask);
                           pd[w][pos] = d21; pi[w][pos] = ja + 64; }
                 pcount += __popcll(m);
                 if (pcount >= SHRINK_AT)
                   pcount = pool_shrink(&pd[w][0], &pi[w][0], pcount, tau, l, lmask); } }
      { const unsigned long long m = __ballot(p2);
        if (m) { if (p2) { const int pos = pcount + __popcll(m & lmask);
                           pd[w][pos] = d22; pi[w][pos] = ja + 128; }
                 pcount += __popcll(m);
                 if (pcount >= SHRINK_AT)
                   pcount = pool_shrink(&pd[w][0], &pi[w][0], pcount, tau, l, lmask); } }
      { const unsigned long long m = __ballot(p3);
        if (m) { if (p3) { const int pos = pcount + __popcll(m & lmask);
                           pd[w][pos] = d23; pi[w][pos] = ja + 192; }
                 pcount += __popcll(m);
                 if (pcount >= SHRINK_AT)
                   pcount = pool_shrink(&pd[w][0], &pi[w][0], pcount, tau, l, lmask); } }
    }
  }
  // ---- tail: proven 64-stride loop
  for (; j0 < hi; j0 += 64) {
    const int j = j0 + l;
    bool pass = false; float d2 = 0.f;
    if (j < hi) {
      const float4 P = xyz4[j];
      const float dx = Q.x - P.x, dy = Q.y - P.y, dz = Q.z - P.z;
      d2 = dx*dx + dy*dy + dz*dz;
      pass = (d2 < tau) && (j != q);
    }
    const unsigned long long m = __ballot(pass);
    if (m) {
      if (pass) {
        const int pos = pcount + __popcll(m & lmask);
        pd[w][pos] = d2; pi[w][pos] = j;
      }
      pcount += __popcll(m);
      if (pcount >= SHRINK_AT)
        pcount = pool_shrink(&pd[w][0], &pi[w][0], pcount, tau, l, lmask);
    }
  }
  pool_final16(&pd[w][0], &pi[w][0], pcount, q, l, knn_idx, knn_d2);
}

__device__ __forceinline__ void load16(const float4* __restrict__ base, int row, float* dst) {
  float4 a = base[row*4+0], b = base[row*4+1], c = base[row*4+2], d = base[row*4+3];
  dst[0]=a.x;  dst[1]=a.y;  dst[2]=a.z;  dst[3]=a.w;
  dst[4]=b.x;  dst[5]=b.y;  dst[6]=b.z;  dst[7]=b.w;
  dst[8]=c.x;  dst[9]=c.y;  dst[10]=c.z; dst[11]=c.w;
  dst[12]=d.x; dst[13]=d.y; dst[14]=d.z; dst[15]=d.w;
}

__device__ __forceinline__ float lrelu(float x) {
  return fmaxf(x, 0.f) + NEG * fminf(x, 0.f);
}

// Layer v1.2: u-decomposition. Phase 1: u = b1 + self@W1_top computed
// cooperatively (lane handles outputs c, c+16; lane15 adds o=32), shared via
// same-wave LDS + lgkmcnt(0). Phase 2: lane=(point,k) computes
// h = u + dk*W1row32 + nbr@W1_mid (528 FMA, W1 via wave-uniform s_loads),
// then the proven shfl k-sum, W2 (LDS), shfl GroupNorm.
__global__ __launch_bounds__(256) void layer_kernel(
    const float* __restrict__ in, const int* __restrict__ knn_idx,
    const float* __restrict__ knn_d2,
    const float* __restrict__ W1, const float* __restrict__ b1,
    const float* __restrict__ W2, const float* __restrict__ b2,
    const float* __restrict__ gamma, const float* __restrict__ beta,
    float* __restrict__ outb) {
  __shared__ float sW2[DIN * D];
  __shared__ float sb2[D], sg[D], sbt[D];
  __shared__ float sU[16][36];                 // per-point u exchange (33 used)
  const int tid = threadIdx.x;
  for (int t = tid; t < DIN * D; t += 256) sW2[t] = W2[t];
  if (tid < D) { sb2[tid] = b2[tid]; sg[tid] = gamma[tid]; sbt[tid] = beta[tid]; }
  __syncthreads();

  const int g = tid >> 4;                      // point slot in block
  const int c = tid & 15;                      // lane-col == neighbor index k
  const int p = blockIdx.x * 16 + g;
  const float4* in4 = (const float4*)in;

  float s[16];
  load16(in4, p, s);                           // own features

  // ---- phase 1: u = b1 + self @ W1_top (outputs c, c+16; lane15 also 32)
  float ua = b1[c], ub = b1[16 + c];
#pragma unroll
  for (int i = 0; i < 16; ++i) {
    ua += s[i] * W1[i * DIN + c];              // coalesced vector loads
    ub += s[i] * W1[i * DIN + 16 + c];
  }
  sU[g][c] = ua;
  sU[g][16 + c] = ub;
  if (c == 15) {
    float uz = b1[32];
#pragma unroll
    for (int i = 0; i < 16; ++i) uz += s[i] * W1[i * DIN + 32];
    sU[g][32] = uz;
  }
  // writers and readers of sU[g] are in the same wave: lgkmcnt(0) suffices
  __asm__ volatile("s_waitcnt lgkmcnt(0)" ::: "memory");

  // ---- phase 2: h = u + dk*W1row32 + nbr @ W1_mid   (per-(point,k) lane)
  const int   nb = knn_idx[p * 16 + c];
  const float dk = knn_d2 [p * 16 + c];
  float nf[16];
  load16(in4, nb, nf);

  float h[DIN];
#pragma unroll
  for (int o = 0; o < DIN; ++o) h[o] = sU[g][o] + dk * W1[32 * DIN + o];
#pragma unroll
  for (int i = 0; i < 16; ++i) {
    const float ni = nf[i];
#pragma unroll
    for (int o = 0; o < DIN; ++o) h[o] += ni * W1[(16 + i) * DIN + o];
  }
#pragma unroll
  for (int o = 0; o < DIN; ++o) h[o] = lrelu(h[o]);

  // sum h over the 16 neighbors (lanes of the 16-group)
#pragma unroll
  for (int o = 0; o < DIN; ++o) {
    float x = h[o];
    x += __shfl_xor(x, 1);
    x += __shfl_xor(x, 2);
    x += __shfl_xor(x, 4);
    x += __shfl_xor(x, 8);
    h[o] = x;
  }

  float m = sb2[c];
#pragma unroll
  for (int i = 0; i < DIN; ++i) m += h[i] * sW2[i * D + c];

  // GroupNorm(groups=2): 8-channel groups -> 8-lane shfl reductions
  float sum = m;
  sum += __shfl_xor(sum, 1); sum += __shfl_xor(sum, 2); sum += __shfl_xor(sum, 4);
  const float mu = sum * 0.125f;
  const float dd = m - mu;
  float sq = dd * dd;
  sq += __shfl_xor(sq, 1); sq += __shfl_xor(sq, 2); sq += __shfl_xor(sq, 4);
  const float var = sq * 0.125f;
  float yv = dd * (1.0f / sqrtf(var + GEPS));
  yv = yv * sg[c] + sbt[c];

  const float selfc = in[p * 16 + c];
  outb[p * 16 + c] = selfc + lrelu(yv);
}

extern "C" void kernel_launch(void* const* d_in, const int* in_sizes, int n_in,
                              void* d_out, int out_size, void* d_ws, size_t ws_size,
                              hipStream_t stream) {
  const float* x     = (const float*)d_in[0];
  const float* yat   = (const float*)d_in[2];
  const float* W1    = (const float*)d_in[3];
  const float* b1    = (const float*)d_in[4];
  const float* W2    = (const float*)d_in[5];
  const float* b2    = (const float*)d_in[6];
  const float* gamma = (const float*)d_in[7];
  const float* beta  = (const float*)d_in[8];
  const int*   xb    = (const int*)d_in[9];
  float* out = (float*)d_out;

  char* ws = (char*)d_ws;
  float4* xyz4 = (float4*)(ws);
  int*    kidx = (int*)  (ws + 262144);
  float*  kd2  = (float*)(ws + 262144 + 1048576);
  float*  bufA = (float*)(ws + 262144 + 2*1048576);
  float*  bufB = (float*)(ws + 262144 + 3*1048576);

  prep_kernel<<<N_PTS / 256, 256, 0, stream>>>(x, xyz4, N_PTS);
  knn_kernel<<<N_PTS / 4, 256, 0, stream>>>(xyz4, xb, kidx, kd2, N_PTS);
  layer_kernel<<<N_PTS / 16, 256, 0, stream>>>(yat,  kidx, kd2,
      W1 + 0*DIN*DIN, b1 + 0*DIN, W2 + 0*DIN*D, b2 + 0*D, gamma + 0*D, beta + 0*D, bufA);
  layer_kernel<<<N_PTS / 16, 256, 0, stream>>>(bufA, kidx, kd2,
      W1 + 1*DIN*DIN, b1 + 1*DIN, W2 + 1*DIN*D, b2 + 1*D, gamma + 1*D, beta + 1*D, bufB);
  layer_kernel<<<N_PTS / 16, 256, 0, stream>>>(bufB, kidx, kd2,
      W1 + 2*DIN*DIN, b1 + 2*DIN, W2 + 2*DIN*D, b2 + 2*D, gamma + 2*D, beta + 2*D, out);
}